// Round 5
// baseline (806.258 us; speedup 1.0000x reference)
//
#include <hip/hip_runtime.h>
#include <math.h>

#define C_DIM 256
#define N_CODE 1024
#define T_TOK 32768
#define MARGIN 8.0e-3f
#define REC_CAP 2048      // per k_score block (128 tok x 256 codes); expect ~640
#define GCAP 8192         // per token-group global list (4 blocks x REC_CAP)

typedef _Float16 half8 __attribute__((ext_vector_type(8)));
typedef float f32x4 __attribute__((ext_vector_type(4)));

// ---------------------------------------------------------------------------
// ws layout (floats):
//   [0, 1024)       esq
//   [1024, 2048)    counts   (memset 0)
//   [2048]          sse      (memset 0)
//   [2052, 2308)    gcnt     (int[256], memset 0)
//   [3072, 35840)   zsq
//   [35840, 68608)  idx (int)
// d_out scratch (fully rewritten by k_out/k_final afterwards):
//   z16   = (_Float16*)d_out            [32768][256] fp16   [0, 16.78MB)
//   cb16  = (_Float16*)d_out + 8388608  [1024][256]  fp16   [16.78, 17.3MB)
//   grecs = (unsigned*)((char*)d_out + 20MB)  [256][GCAP]   [20.97, 29.36MB)
//   (outidx region at 33.55MB+ untouched by scratch)
// ---------------------------------------------------------------------------

__global__ __launch_bounds__(256) void k_esqcb(const float* __restrict__ cb,
    float* __restrict__ esq, _Float16* __restrict__ cb16)
{
    int n = blockIdx.x * 256 + threadIdx.x;
    const float* row = cb + (size_t)n * C_DIM;
    float s = 0.0f;
    for (int k = 0; k < C_DIM; k += 8) {
        float4 a = *(const float4*)(row + k);
        float4 b = *(const float4*)(row + k + 4);
        s = fmaf(a.x, a.x, s); s = fmaf(a.y, a.y, s);
        s = fmaf(a.z, a.z, s); s = fmaf(a.w, a.w, s);
        s = fmaf(b.x, b.x, s); s = fmaf(b.y, b.y, s);
        s = fmaf(b.z, b.z, s); s = fmaf(b.w, b.w, s);
        _Float16 p[8];
        p[0] = (_Float16)a.x; p[1] = (_Float16)a.y; p[2] = (_Float16)a.z; p[3] = (_Float16)a.w;
        p[4] = (_Float16)b.x; p[5] = (_Float16)b.y; p[6] = (_Float16)b.z; p[7] = (_Float16)b.w;
        *(half8*)(cb16 + (size_t)n * C_DIM + k) = *(half8*)p;
    }
    esq[n] = s;
}

// Transpose z -> token-major fp16 + zsq bit-replicating XLA's row reduce.
// VALIDATED bit-exact in round 4 (absmax == 0.0). Do not alter the
// mul/add order, contraction-off, or the shfl tree.
__global__ __launch_bounds__(256) void k_prep(const float* __restrict__ z,
    _Float16* __restrict__ z16, float* __restrict__ zsq)
{
#pragma clang fp contract(off)
    __shared__ float tile[64 * 68];
    int tid = threadIdx.x;
    int t0 = blockIdx.x * 64;
    int b = t0 >> 10, hw0 = t0 & 1023;
    int t = tid >> 2, part = tid & 3;
    float P[4][4];
    #pragma unroll
    for (int cc = 0; cc < 4; ++cc)
        #pragma unroll
        for (int u = 0; u < 4; ++u) P[cc][u] = 0.0f;

    #pragma unroll
    for (int cc = 0; cc < 4; ++cc) {
        int c0 = cc * 64;
        __syncthreads();
        #pragma unroll
        for (int q = 0; q < 4; ++q) {
            int fi = tid + 256 * q;
            int c = fi >> 4, h4 = (fi & 15) * 4;
            float4 v = *(const float4*)(z + ((size_t)(b * C_DIM + c0 + c)) * 1024 + hw0 + h4);
            *(float4*)&tile[c * 68 + h4] = v;
        }
        __syncthreads();
        _Float16 pack[16];
        #pragma unroll
        for (int j = 0; j < 16; ++j) {
            float v = tile[(part * 16 + j) * 68 + t];
            float m = v * v;
            P[cc][j >> 2] = P[cc][j >> 2] + m;
            pack[j] = (_Float16)v;
        }
        *(half8*)(z16 + (size_t)(t0 + t) * C_DIM + c0 + part * 16)     = *(half8*)&pack[0];
        *(half8*)(z16 + (size_t)(t0 + t) * C_DIM + c0 + part * 16 + 8) = *(half8*)&pack[8];
    }
    float Bv[4], Cv[4], Dv[4];
    #pragma unroll
    for (int u = 0; u < 4; ++u) {
        float A0 = P[0][u] + P[2][u];
        float A1 = P[1][u] + P[3][u];
        Bv[u] = A0 + A1;
    }
    #pragma unroll
    for (int u = 0; u < 4; ++u) Cv[u] = Bv[u] + __shfl_xor(Bv[u], 2, 64);
    #pragma unroll
    for (int u = 0; u < 4; ++u) Dv[u] = Cv[u] + __shfl_xor(Cv[u], 1, 64);
    float E0 = Dv[0] + Dv[2];
    float E1 = Dv[1] + Dv[3];
    float F = E0 + E1;
    if (part == 0) zsq[t0 + t] = F;
}

// Approx MFMA scoring, code-split x4: block (grp, q) scores 128 tokens
// against codes [q*256, q*256+256) as 2 chunks of 128. Margin capture per
// block (local-min threshold >= global: union of captures contains true
// argmin). Candidates flushed to global per-group list.
__global__ __launch_bounds__(256, 4) void k_score(
    const _Float16* __restrict__ z16, const _Float16* __restrict__ cb16,
    const float* __restrict__ esq,
    unsigned* __restrict__ grecs, int* __restrict__ gcnt)
{
    __shared__ unsigned recs[REC_CAP];
    __shared__ int cnt, sbase;

    int tid = threadIdx.x;
    int grp = blockIdx.x >> 2, q = blockIdx.x & 3;
    int t0 = grp * 128;
    int lane = tid & 63;
    int w = tid >> 6;
    int wr = w >> 1, wc = w & 1;
    int l15 = lane & 15, g4 = lane >> 4;

    if (tid == 0) cnt = 0;
    __syncthreads();

    float runm[4][4];
    #pragma unroll
    for (int i = 0; i < 4; ++i)
        #pragma unroll
        for (int r = 0; r < 4; ++r) runm[i][r] = INFINITY;

    const _Float16* Abase = z16 + (size_t)(t0 + wr * 64 + l15) * C_DIM + g4 * 8;

    for (int chunk = 0; chunk < 2; ++chunk) {
        int n0 = q * 256 + chunk * 128;
        const _Float16* Bb = cb16 + (size_t)(n0 + wc * 64 + l15) * C_DIM + g4 * 8;
        f32x4 acc[4][4];
        #pragma unroll
        for (int i = 0; i < 4; ++i)
            #pragma unroll
            for (int j = 0; j < 4; ++j) acc[i][j] = (f32x4){0.f, 0.f, 0.f, 0.f};

        float eq[4];
        #pragma unroll
        for (int j = 0; j < 4; ++j) eq[j] = esq[n0 + wc * 64 + j * 16 + l15];

        #pragma unroll
        for (int ks = 0; ks < 8; ++ks) {
            half8 af[4], bf[4];
            #pragma unroll
            for (int i = 0; i < 4; ++i)
                af[i] = *(const half8*)(Abase + (size_t)(i * 16) * C_DIM + ks * 32);
            #pragma unroll
            for (int j = 0; j < 4; ++j)
                bf[j] = *(const half8*)(Bb + (size_t)(j * 16) * C_DIM + ks * 32);
            #pragma unroll
            for (int i = 0; i < 4; ++i)
                #pragma unroll
                for (int j = 0; j < 4; ++j)
                    acc[i][j] = __builtin_amdgcn_mfma_f32_16x16x32_f16(af[i], bf[j], acc[i][j], 0, 0, 0);
        }
        #pragma unroll
        for (int i = 0; i < 4; ++i) {
            #pragma unroll
            for (int r = 0; r < 4; ++r) {
                float g0 = eq[0] - 2.0f * acc[i][0][r];
                float g1 = eq[1] - 2.0f * acc[i][1][r];
                float g2 = eq[2] - 2.0f * acc[i][2][r];
                float g3 = eq[3] - 2.0f * acc[i][3][r];
                float m = fminf(fminf(g0, g1), fminf(g2, g3));
                float bm = m;
                bm = fminf(bm, __shfl_xor(bm, 1, 64));
                bm = fminf(bm, __shfl_xor(bm, 2, 64));
                bm = fminf(bm, __shfl_xor(bm, 4, 64));
                bm = fminf(bm, __shfl_xor(bm, 8, 64));
                float rm = fminf(runm[i][r], bm);
                runm[i][r] = rm;
                float thr = rm + MARGIN;
                if (m <= thr) {
                    int tl = wr * 64 + i * 16 + g4 * 4 + r;
                    int nb = n0 + wc * 64 + l15;
                    if (g0 <= thr) { int p = atomicAdd(&cnt, 1); if (p < REC_CAP) recs[p] = (unsigned)((tl << 10) | nb); }
                    if (g1 <= thr) { int p = atomicAdd(&cnt, 1); if (p < REC_CAP) recs[p] = (unsigned)((tl << 10) | (nb + 16)); }
                    if (g2 <= thr) { int p = atomicAdd(&cnt, 1); if (p < REC_CAP) recs[p] = (unsigned)((tl << 10) | (nb + 32)); }
                    if (g3 <= thr) { int p = atomicAdd(&cnt, 1); if (p < REC_CAP) recs[p] = (unsigned)((tl << 10) | (nb + 48)); }
                }
            }
        }
    }
    __syncthreads();
    int c = cnt; if (c > REC_CAP) c = REC_CAP;
    if (tid == 0) sbase = atomicAdd(&gcnt[grp], c);
    __syncthreads();
    int base = sbase;
    for (int i2 = tid; i2 < c; i2 += 256) {
        int dst = base + i2;
        if (dst < GCAP) grecs[(size_t)grp * GCAP + dst] = recs[i2];
    }
}

// Exact fp32 rescore: authority for every output index. Block = 64 tokens
// (half of a token-group); scans the group's candidate list, filters by
// 32-token sub-pass, stages fp32 z in LDS (coalesced), packed u64 atomicMin
// (ties -> lowest code index, matching jnp.argmin).
__global__ __launch_bounds__(256) void k_rescore(
    const float* __restrict__ z, const float* __restrict__ cb,
    const float* __restrict__ esq, const float* __restrict__ zsq,
    const unsigned* __restrict__ grecs, const int* __restrict__ gcnt,
    int* __restrict__ idxout)
{
    __shared__ float zl[32][260];
    __shared__ unsigned long long keys[64];
    int tid = threadIdx.x;
    int grp = blockIdx.x >> 1, h = blockIdx.x & 1;
    int t0 = grp * 128 + h * 64;
    int b = t0 >> 10, hw0 = t0 & 1023;
    int lane = tid & 63, w = tid >> 6;

    if (tid < 64) keys[tid] = 0xFFFFFFFFFFFFFFFFULL;
    int ncand = gcnt[grp]; if (ncand > GCAP) ncand = GCAP;
    const unsigned* rl = grecs + (size_t)grp * GCAP;

    for (int tg = 0; tg < 2; ++tg) {
        __syncthreads();
        #pragma unroll 4
        for (int it = 0; it < 32; ++it) {
            int fi = tid + 256 * it;
            int tok = fi & 31, cch = fi >> 5;
            zl[tok][cch] = z[((size_t)(b * C_DIM + cch)) * 1024 + hw0 + tg * 32 + tok];
        }
        __syncthreads();
        int want = h * 2 + tg;                 // tl>>5 selector
        for (int r0 = w * 4; r0 < ncand; r0 += 16) {
            #pragma unroll
            for (int u = 0; u < 4; ++u) {
                int r = r0 + u;
                if (r >= ncand) break;         // wave-uniform
                unsigned rec = rl[r];          // broadcast
                int tl = (int)(rec >> 10);
                if ((tl >> 5) != want) continue;  // wave-uniform
                int nn = (int)(rec & 1023u);
                f32x4 zv = *(const f32x4*)&zl[tl & 31][lane * 4];
                f32x4 cv = *(const f32x4*)(cb + (size_t)nn * C_DIM + lane * 4);
                float s = zv[0] * cv[0];
                s = fmaf(zv[1], cv[1], s);
                s = fmaf(zv[2], cv[2], s);
                s = fmaf(zv[3], cv[3], s);
                #pragma unroll
                for (int mm = 1; mm < 64; mm <<= 1) s += __shfl_xor(s, mm, 64);
                float d = (zsq[grp * 128 + tl] + esq[nn]) - 2.0f * s;
                unsigned long long key = ((unsigned long long)__float_as_uint(d) << 32) | (unsigned)nn;
                if (lane == 0) atomicMin(&keys[tl & 63], key);
            }
        }
    }
    __syncthreads();
    if (tid < 64) idxout[t0 + tid] = (int)(keys[tid] & 1023ULL);
}

// Gather z_q, write z_q_st = fl(z + fl(z_q - z)), float indices, histogram, SSE.
__global__ __launch_bounds__(256) void k_out(
    const float* __restrict__ z, const float* __restrict__ cb,
    const int* __restrict__ idx, float* __restrict__ outq,
    float* __restrict__ outidx, float* __restrict__ counts,
    float* __restrict__ sse)
{
    __shared__ float rows[32][260];
    __shared__ float red[4];
    int tid = threadIdx.x;
    int t0 = blockIdx.x * 32;
    int b = t0 >> 10, hw0 = t0 & 1023;
    {
        int tr = tid & 31, p = tid >> 5;
        int n = idx[t0 + tr];
        const float* src = cb + (size_t)n * C_DIM + p * 32;
        #pragma unroll
        for (int q = 0; q < 8; ++q) {
            float4 v = *(const float4*)(src + q * 4);
            *(float4*)&rows[tr][p * 32 + q * 4] = v;
        }
    }
    if (tid < 32) {
        int n = idx[t0 + tid];
        outidx[t0 + tid] = (float)n;
        atomicAdd(&counts[n], 1.0f);
    }
    __syncthreads();
    int tl = tid & 31, c4 = tid >> 5;
    float part = 0.0f;
    for (int cc = 0; cc < 32; ++cc) {
        int c = cc * 8 + c4;
        size_t off = ((size_t)(b * C_DIM + c)) * 1024 + hw0 + tl;
        float zv = z[off];
        float qv = rows[tl][c];
        float dd = qv - zv;
        outq[off] = zv + dd;
        part = fmaf(dd, dd, part);
    }
    #pragma unroll
    for (int m = 1; m < 64; m <<= 1) part += __shfl_xor(part, m, 64);
    if ((tid & 63) == 0) red[tid >> 6] = part;
    __syncthreads();
    if (tid == 0) atomicAdd(sse, red[0] + red[1] + red[2] + red[3]);
}

__global__ __launch_bounds__(1024) void k_final(
    const float* __restrict__ counts, const float* __restrict__ sse,
    float* __restrict__ outsc)
{
    __shared__ float red[16];
    int tid = threadIdx.x;
    float p = counts[tid] * (1.0f / 32768.0f);
    float term = p * logf(p + 1e-10f);
    #pragma unroll
    for (int m = 1; m < 64; m <<= 1) term += __shfl_xor(term, m, 64);
    if ((tid & 63) == 0) red[tid >> 6] = term;
    __syncthreads();
    if (tid == 0) {
        float s = 0.0f;
        #pragma unroll
        for (int i = 0; i < 16; ++i) s += red[i];
        float m = sse[0] / 8388608.0f;
        outsc[0] = m + 0.25f * m;
        outsc[1] = expf(-s);
    }
}

extern "C" void kernel_launch(void* const* d_in, const int* in_sizes, int n_in,
                              void* d_out, int out_size, void* d_ws, size_t ws_size,
                              hipStream_t stream) {
    const float* z  = (const float*)d_in[0];
    const float* cb = (const float*)d_in[1];
    float* wsf    = (float*)d_ws;
    float* esq    = wsf;
    float* counts = wsf + 1024;
    float* sse    = wsf + 2048;
    int*   gcnt   = (int*)(wsf + 2052);
    float* zsq    = wsf + 3072;
    int*   idx    = (int*)(wsf + 3072 + 32768);

    float* outq   = (float*)d_out;
    float* outidx = outq + 8388608;
    float* outsc  = outq + 8388608 + 32768;

    _Float16* z16   = (_Float16*)d_out;
    _Float16* cb16  = (_Float16*)d_out + 8388608;
    unsigned* grecs = (unsigned*)((char*)d_out + 20971520);  // 20MB..28MB

    // zero counts(1024) + sse(1) + pad + gcnt(256 ints): floats [1024,2308)
    hipMemsetAsync(counts, 0, (2308 - 1024) * sizeof(float), stream);
    k_esqcb<<<4, 256, 0, stream>>>(cb, esq, cb16);
    k_prep<<<512, 256, 0, stream>>>(z, z16, zsq);
    k_score<<<1024, 256, 0, stream>>>(z16, cb16, esq, grecs, gcnt);
    k_rescore<<<512, 256, 0, stream>>>(z, cb, esq, zsq, grecs, gcnt, idx);
    k_out<<<1024, 256, 0, stream>>>(z, cb, idx, outq, outidx, counts, sse);
    k_final<<<1, 1024, 0, stream>>>(counts, sse, outsc);
}

// Round 7
// 325.014 us; speedup vs baseline: 2.4807x; 2.4807x over previous
//
#include <hip/hip_runtime.h>
#include <math.h>

#define C_DIM 256
#define N_CODE 1024
#define T_TOK 32768
#define MARGIN 2.5e-3f     // > 2x rigorous fp16-score error bound (incl. denorm flush)
#define CAP 64             // per-token candidate slots (expect ~10-15)

typedef _Float16 half8 __attribute__((ext_vector_type(8)));
typedef float f32x4 __attribute__((ext_vector_type(4)));

// async global->LDS 16B: dest = wave-uniform base + lane*16 (linear); source per-lane
#define GLDS16(gsrc, ldst) __builtin_amdgcn_global_load_lds( \
    (const __attribute__((address_space(1))) void*)(gsrc),   \
    (__attribute__((address_space(3))) void*)(ldst), 16, 0, 0)

// ---------------------------------------------------------------------------
// ws layout (floats):
//   [0, 1024)       esq
//   [1024, 2048)    counts   (memset 0)
//   [2048]          sse      (memset 0)
//   [3072, 35840)   zsq
//   [35840, 68608)  idx (int)
// d_out scratch (fully rewritten by k_out/k_final afterwards):
//   z16   = (_Float16*)d_out           [32768][256] fp16   [0, 16.78MB)
//   cb16  = (_Float16*)d_out + 8388608 [1024][256]  fp16   [16.78, 17.30MB)
//   gcand = (int*)((char*)d_out + 20971520)  [32768][CAP]  [20.97, 29.36MB)
//   pcnt  = (int*)((char*)d_out + 29360128)  [32768]       [29.36, 29.49MB) memset 0
// ---------------------------------------------------------------------------

__global__ __launch_bounds__(256) void k_esqcb(const float* __restrict__ cb,
    float* __restrict__ esq, _Float16* __restrict__ cb16)
{
    int n = blockIdx.x * 256 + threadIdx.x;
    const float* row = cb + (size_t)n * C_DIM;
    float s = 0.0f;
    for (int k = 0; k < C_DIM; k += 8) {
        float4 a = *(const float4*)(row + k);
        float4 b = *(const float4*)(row + k + 4);
        s = fmaf(a.x, a.x, s); s = fmaf(a.y, a.y, s);
        s = fmaf(a.z, a.z, s); s = fmaf(a.w, a.w, s);
        s = fmaf(b.x, b.x, s); s = fmaf(b.y, b.y, s);
        s = fmaf(b.z, b.z, s); s = fmaf(b.w, b.w, s);
        _Float16 p[8];
        p[0] = (_Float16)a.x; p[1] = (_Float16)a.y; p[2] = (_Float16)a.z; p[3] = (_Float16)a.w;
        p[4] = (_Float16)b.x; p[5] = (_Float16)b.y; p[6] = (_Float16)b.z; p[7] = (_Float16)b.w;
        *(half8*)(cb16 + (size_t)n * C_DIM + k) = *(half8*)p;
    }
    esq[n] = s;
}

// Transpose z -> token-major fp16 + zsq bit-replicating XLA's row reduce.
// VALIDATED bit-exact (r4, absmax == 0.0). Do not alter mul/add order,
// contraction-off, or the shfl tree.
__global__ __launch_bounds__(256) void k_prep(const float* __restrict__ z,
    _Float16* __restrict__ z16, float* __restrict__ zsq)
{
#pragma clang fp contract(off)
    __shared__ float tile[64 * 68];
    int tid = threadIdx.x;
    int t0 = blockIdx.x * 64;
    int b = t0 >> 10, hw0 = t0 & 1023;
    int t = tid >> 2, part = tid & 3;
    float P[4][4];
    #pragma unroll
    for (int cc = 0; cc < 4; ++cc)
        #pragma unroll
        for (int u = 0; u < 4; ++u) P[cc][u] = 0.0f;

    #pragma unroll
    for (int cc = 0; cc < 4; ++cc) {
        int c0 = cc * 64;
        __syncthreads();
        #pragma unroll
        for (int q = 0; q < 4; ++q) {
            int fi = tid + 256 * q;
            int c = fi >> 4, h4 = (fi & 15) * 4;
            float4 v = *(const float4*)(z + ((size_t)(b * C_DIM + c0 + c)) * 1024 + hw0 + h4);
            *(float4*)&tile[c * 68 + h4] = v;
        }
        __syncthreads();
        _Float16 pack[16];
        #pragma unroll
        for (int j = 0; j < 16; ++j) {
            float v = tile[(part * 16 + j) * 68 + t];
            float m = v * v;
            P[cc][j >> 2] = P[cc][j >> 2] + m;
            pack[j] = (_Float16)v;
        }
        *(half8*)(z16 + (size_t)(t0 + t) * C_DIM + c0 + part * 16)     = *(half8*)&pack[0];
        *(half8*)(z16 + (size_t)(t0 + t) * C_DIM + c0 + part * 16 + 8) = *(half8*)&pack[8];
    }
    float Bv[4], Cv[4], Dv[4];
    #pragma unroll
    for (int u = 0; u < 4; ++u) {
        float A0 = P[0][u] + P[2][u];
        float A1 = P[1][u] + P[3][u];
        Bv[u] = A0 + A1;
    }
    #pragma unroll
    for (int u = 0; u < 4; ++u) Cv[u] = Bv[u] + __shfl_xor(Bv[u], 2, 64);
    #pragma unroll
    for (int u = 0; u < 4; ++u) Dv[u] = Cv[u] + __shfl_xor(Cv[u], 1, 64);
    float E0 = Dv[0] + Dv[2];
    float E1 = Dv[1] + Dv[3];
    float F = E0 + E1;
    if (part == 0) zsq[t0 + t] = F;
}

// MFMA scoring with double-buffered LDS staging (global_load_lds 16B,
// counted vmcnt, raw barriers). Block (grp,q): 128 tokens x 256 codes,
// 16 iters (chunk 0..1 x ks 0..7), wave tile 64x64.
// LDS swizzle: physical slot = logical ^ ((row>>1)&3), applied on the
// pre-swizzled GLOBAL source (stage) and on the ds_read slot (read).
// Fragment operands are bit-identical to the r4-validated direct loads.
__global__ __launch_bounds__(256, 3) void k_score(
    const _Float16* __restrict__ z16, const _Float16* __restrict__ cb16,
    const float* __restrict__ esq,
    int* __restrict__ gcand, int* __restrict__ pcnt)
{
    __shared__ _Float16 ldsA[2][4096];   // [buf][row*32 + slot*8], 128 rows x 64B
    __shared__ _Float16 ldsB[2][4096];

    int tid = threadIdx.x;
    // XCD-bijective swizzle (1024 % 8 == 0): q-siblings share one XCD's L2
    int bid = blockIdx.x;
    int nb = (bid & 7) * 128 + (bid >> 3);
    int grp = nb >> 2, q = nb & 3;
    int t0 = grp * 128;
    int lane = tid & 63;
    int w = tid >> 6;
    int wr = w >> 1, wc = w & 1;
    int l15 = lane & 15, g4 = lane >> 4;

    // staging lane constants: row_in_inst = lane>>2, source slot pre-swizzled
    const int sslot8 = ((lane & 3) ^ ((lane >> 3) & 3)) * 8;
    const size_t arow = (size_t)(t0 + w * 32 + (lane >> 2)) * C_DIM + sslot8;
    const size_t brow = (size_t)(w * 32 + (lane >> 2)) * C_DIM + sslot8;

    float runm[4][4];
    #pragma unroll
    for (int i = 0; i < 4; ++i)
        #pragma unroll
        for (int r = 0; r < 4; ++r) runm[i][r] = INFINITY;

    f32x4 acc[4][4];

    #define STAGE(mm, dd) do {                                              \
        int k0_ = ((mm) & 7) * 32;                                          \
        size_t nbase_ = (size_t)(q * 256 + ((mm) >> 3) * 128) * C_DIM;      \
        _Pragma("unroll")                                                   \
        for (int it_ = 0; it_ < 2; ++it_) {                                 \
            GLDS16(z16 + arow + (size_t)it_ * 16 * C_DIM + k0_,             \
                   &ldsA[dd][(w * 32 + it_ * 16) * 32]);                    \
            GLDS16(cb16 + nbase_ + brow + (size_t)it_ * 16 * C_DIM + k0_,   \
                   &ldsB[dd][(w * 32 + it_ * 16) * 32]);                    \
        }                                                                   \
    } while (0)

    STAGE(0, 0);
    const int po = (g4 ^ ((l15 >> 1) & 3)) * 8;   // read-side slot swizzle

    for (int m = 0; m < 16; ++m) {
        int d = m & 1;
        if ((m & 7) == 0) {
            #pragma unroll
            for (int i = 0; i < 4; ++i)
                #pragma unroll
                for (int j = 0; j < 4; ++j) acc[i][j] = (f32x4){0.f, 0.f, 0.f, 0.f};
        }
        if (m < 15) {
            STAGE(m + 1, d ^ 1);
            asm volatile("s_waitcnt vmcnt(4)" ::: "memory");   // current buf's DMA done
        } else {
            asm volatile("s_waitcnt vmcnt(0)" ::: "memory");
        }
        asm volatile("s_barrier" ::: "memory");                 // all waves: buf ready

        half8 af[4], bf[4];
        #pragma unroll
        for (int i = 0; i < 4; ++i)
            af[i] = *(const half8*)&ldsA[d][(wr * 64 + i * 16 + l15) * 32 + po];
        #pragma unroll
        for (int j = 0; j < 4; ++j)
            bf[j] = *(const half8*)&ldsB[d][(wc * 64 + j * 16 + l15) * 32 + po];
        asm volatile("s_waitcnt lgkmcnt(0)" ::: "memory");      // frags in regs
        asm volatile("s_barrier" ::: "memory");                 // reads done -> buf reusable

        #pragma unroll
        for (int i = 0; i < 4; ++i)
            #pragma unroll
            for (int j = 0; j < 4; ++j)
                acc[i][j] = __builtin_amdgcn_mfma_f32_16x16x32_f16(af[i], bf[j], acc[i][j], 0, 0, 0);

        if ((m & 7) == 7) {   // fold chunk: g = esq - 2*s, capture margin set
            int n0 = q * 256 + (m >> 3) * 128;
            float eq[4];
            #pragma unroll
            for (int j = 0; j < 4; ++j) eq[j] = esq[n0 + wc * 64 + j * 16 + l15];
            #pragma unroll
            for (int i = 0; i < 4; ++i) {
                #pragma unroll
                for (int r = 0; r < 4; ++r) {
                    float g0 = eq[0] - 2.0f * acc[i][0][r];
                    float g1 = eq[1] - 2.0f * acc[i][1][r];
                    float g2 = eq[2] - 2.0f * acc[i][2][r];
                    float g3 = eq[3] - 2.0f * acc[i][3][r];
                    float mn = fminf(fminf(g0, g1), fminf(g2, g3));
                    float bm = mn;
                    bm = fminf(bm, __shfl_xor(bm, 1, 64));
                    bm = fminf(bm, __shfl_xor(bm, 2, 64));
                    bm = fminf(bm, __shfl_xor(bm, 4, 64));
                    bm = fminf(bm, __shfl_xor(bm, 8, 64));
                    float rm = fminf(runm[i][r], bm);
                    runm[i][r] = rm;
                    float thr = rm + MARGIN;
                    if (mn <= thr) {
                        int gt = t0 + wr * 64 + i * 16 + g4 * 4 + r;
                        int nbv = n0 + wc * 64 + l15;
                        if (g0 <= thr) { int p = atomicAdd(&pcnt[gt], 1); if (p < CAP) gcand[(size_t)gt * CAP + p] = nbv; }
                        if (g1 <= thr) { int p = atomicAdd(&pcnt[gt], 1); if (p < CAP) gcand[(size_t)gt * CAP + p] = nbv + 16; }
                        if (g2 <= thr) { int p = atomicAdd(&pcnt[gt], 1); if (p < CAP) gcand[(size_t)gt * CAP + p] = nbv + 32; }
                        if (g3 <= thr) { int p = atomicAdd(&pcnt[gt], 1); if (p < CAP) gcand[(size_t)gt * CAP + p] = nbv + 48; }
                    }
                }
            }
        }
    }
    #undef STAGE
}

// Exact fp32 rescore: authority for every output index. Block = 64 tokens in
// 2 subpasses of 32 (fp32 z staged in LDS). Per wave: 8 tokens; per token:
// rounds of 8 candidates, one per 8-lane group (32 ch/lane fma + 3-step
// xor-reduce). Packed u64 LDS atomicMin -> ties pick lowest code index.
__global__ __launch_bounds__(256) void k_rescore(
    const float* __restrict__ z, const float* __restrict__ cb,
    const float* __restrict__ esq, const float* __restrict__ zsq,
    const int* __restrict__ gcand, const int* __restrict__ pcnt,
    int* __restrict__ idxout)
{
    __shared__ float zl[32 * 264];
    __shared__ unsigned long long keys[32];
    int tid = threadIdx.x;
    int t0 = blockIdx.x * 64;
    int b = t0 >> 10, hw0 = t0 & 1023;
    int lane = tid & 63, w = tid >> 6;
    int g = lane >> 3, gl = lane & 7;

    for (int sp = 0; sp < 2; ++sp) {
        int ts = t0 + sp * 32;
        __syncthreads();
        if (tid < 32) keys[tid] = 0xFFFFFFFFFFFFFFFFULL;
        #pragma unroll 4
        for (int it = 0; it < 32; ++it) {
            int fi = tid + 256 * it;
            int tok = fi & 31, cch = fi >> 5;
            zl[tok * 264 + cch] = z[((size_t)(b * C_DIM + cch)) * 1024 + hw0 + sp * 32 + tok];
        }
        __syncthreads();
        for (int j = 0; j < 8; ++j) {
            int tok = w + 4 * j;
            int tg = ts + tok;
            int Kt = pcnt[tg]; if (Kt > CAP) Kt = CAP;
            const int* cl = gcand + (size_t)tg * CAP;
            float zq = zsq[tg];
            int rounds = (Kt + 7) >> 3;
            for (int r = 0; r < rounds; ++r) {
                int ci = r * 8 + g;
                bool act = (ci < Kt);
                int nn = act ? cl[ci] : 0;
                const float* crow = cb + (size_t)nn * C_DIM + gl * 32;
                const float* zrow = zl + tok * 264 + gl * 32;
                float s = 0.0f;
                #pragma unroll
                for (int qq = 0; qq < 8; ++qq) {
                    f32x4 cv = *(const f32x4*)(crow + qq * 4);
                    f32x4 zv = *(const f32x4*)(zrow + qq * 4);
                    s = fmaf(zv[0], cv[0], s);
                    s = fmaf(zv[1], cv[1], s);
                    s = fmaf(zv[2], cv[2], s);
                    s = fmaf(zv[3], cv[3], s);
                }
                s += __shfl_xor(s, 1, 64);
                s += __shfl_xor(s, 2, 64);
                s += __shfl_xor(s, 4, 64);
                if (gl == 0 && act) {
                    float d = (zq + esq[nn]) - 2.0f * s;
                    unsigned long long key =
                        ((unsigned long long)__float_as_uint(d) << 32) | (unsigned)nn;
                    atomicMin(&keys[tok], key);
                }
            }
        }
        __syncthreads();
        if (tid < 32) idxout[ts + tid] = (int)(keys[tid] & 1023ULL);
    }
}

// Gather z_q, write z_q_st = fl(z + fl(z_q - z)), float indices, histogram, SSE.
__global__ __launch_bounds__(256) void k_out(
    const float* __restrict__ z, const float* __restrict__ cb,
    const int* __restrict__ idx, float* __restrict__ outq,
    float* __restrict__ outidx, float* __restrict__ counts,
    float* __restrict__ sse)
{
    __shared__ float rows[32][260];
    __shared__ float red[4];
    int tid = threadIdx.x;
    int t0 = blockIdx.x * 32;
    int b = t0 >> 10, hw0 = t0 & 1023;
    {
        int tr = tid & 31, p = tid >> 5;
        int n = idx[t0 + tr];
        const float* src = cb + (size_t)n * C_DIM + p * 32;
        #pragma unroll
        for (int q = 0; q < 8; ++q) {
            float4 v = *(const float4*)(src + q * 4);
            *(float4*)&rows[tr][p * 32 + q * 4] = v;
        }
    }
    if (tid < 32) {
        int n = idx[t0 + tid];
        outidx[t0 + tid] = (float)n;
        atomicAdd(&counts[n], 1.0f);
    }
    __syncthreads();
    int tl = tid & 31, c4 = tid >> 5;
    float part = 0.0f;
    for (int cc = 0; cc < 32; ++cc) {
        int c = cc * 8 + c4;
        size_t off = ((size_t)(b * C_DIM + c)) * 1024 + hw0 + tl;
        float zv = z[off];
        float qv = rows[tl][c];
        float dd = qv - zv;
        outq[off] = zv + dd;
        part = fmaf(dd, dd, part);
    }
    #pragma unroll
    for (int m = 1; m < 64; m <<= 1) part += __shfl_xor(part, m, 64);
    if ((tid & 63) == 0) red[tid >> 6] = part;
    __syncthreads();
    if (tid == 0) atomicAdd(sse, red[0] + red[1] + red[2] + red[3]);
}

__global__ __launch_bounds__(1024) void k_final(
    const float* __restrict__ counts, const float* __restrict__ sse,
    float* __restrict__ outsc)
{
    __shared__ float red[16];
    int tid = threadIdx.x;
    float p = counts[tid] * (1.0f / 32768.0f);
    float term = p * logf(p + 1e-10f);
    #pragma unroll
    for (int m = 1; m < 64; m <<= 1) term += __shfl_xor(term, m, 64);
    if ((tid & 63) == 0) red[tid >> 6] = term;
    __syncthreads();
    if (tid == 0) {
        float s = 0.0f;
        #pragma unroll
        for (int i = 0; i < 16; ++i) s += red[i];
        float m = sse[0] / 8388608.0f;
        outsc[0] = m + 0.25f * m;
        outsc[1] = expf(-s);
    }
}

extern "C" void kernel_launch(void* const* d_in, const int* in_sizes, int n_in,
                              void* d_out, int out_size, void* d_ws, size_t ws_size,
                              hipStream_t stream) {
    const float* z  = (const float*)d_in[0];
    const float* cb = (const float*)d_in[1];
    float* wsf    = (float*)d_ws;
    float* esq    = wsf;
    float* counts = wsf + 1024;
    float* sse    = wsf + 2048;
    float* zsq    = wsf + 3072;
    int*   idx    = (int*)(wsf + 3072 + 32768);

    float* outq   = (float*)d_out;
    float* outidx = outq + 8388608;
    float* outsc  = outq + 8388608 + 32768;

    _Float16* z16   = (_Float16*)d_out;
    _Float16* cb16  = (_Float16*)d_out + 8388608;
    int*      gcand = (int*)((char*)d_out + 20971520);   // 32768*64*4 = 8.39MB
    int*      pcnt  = (int*)((char*)d_out + 29360128);   // ends 29.49MB < outidx @33.55MB

    hipMemsetAsync(counts, 0, 1025 * sizeof(float), stream);   // counts + sse
    hipMemsetAsync(pcnt, 0, T_TOK * sizeof(int), stream);
    k_esqcb<<<4, 256, 0, stream>>>(cb, esq, cb16);
    k_prep<<<512, 256, 0, stream>>>(z, z16, zsq);
    k_score<<<1024, 256, 0, stream>>>(z16, cb16, esq, gcand, pcnt);
    k_rescore<<<512, 256, 0, stream>>>(z, cb, esq, zsq, gcand, pcnt, idx);
    k_out<<<1024, 256, 0, stream>>>(z, cb, idx, outq, outidx, counts, sse);
    k_final<<<1, 1024, 0, stream>>>(counts, sse, outsc);
}